// Round 1
// baseline (205.824 us; speedup 1.0000x reference)
//
#include <hip/hip_runtime.h>
#include <cstdint>

// JAX PRNG mode: 1 = jax_threefry_partitionable=True (modern default),
// 0 = legacy iota-halves mode. Flip if arcs mismatch.
#ifndef JAX_PARTITIONABLE
#define JAX_PARTITIONABLE 1
#endif

__device__ __forceinline__ uint32_t rotl32_(uint32_t v, int d) {
  return (v << d) | (v >> (32 - d));
}

// Threefry-2x32, 20 rounds, exactly JAX's schedule.
__device__ __forceinline__ void tf2x32(uint32_t k0, uint32_t k1,
                                       uint32_t x0, uint32_t x1,
                                       uint32_t& o0, uint32_t& o1) {
  const uint32_t k2 = k0 ^ k1 ^ 0x1BD11BDAu;
  x0 += k0; x1 += k1;
#define TF4(a,b,c,d) \
  x0 += x1; x1 = rotl32_(x1,a); x1 ^= x0; \
  x0 += x1; x1 = rotl32_(x1,b); x1 ^= x0; \
  x0 += x1; x1 = rotl32_(x1,c); x1 ^= x0; \
  x0 += x1; x1 = rotl32_(x1,d); x1 ^= x0;
  TF4(13,15,26,6)
  x0 += k1; x1 += k2 + 1u;
  TF4(17,29,16,24)
  x0 += k2; x1 += k0 + 2u;
  TF4(13,15,26,6)
  x0 += k0; x1 += k1 + 3u;
  TF4(17,29,16,24)
  x0 += k1; x1 += k2 + 4u;
  TF4(13,15,26,6)
  x0 += k2; x1 += k0 + 5u;
#undef TF4
  o0 = x0; o1 = x1;
}

// XLA lowers logistic to 0.5 + 0.5*tanh(0.5*x)
__device__ __forceinline__ float sigf(float x) {
  return 0.5f * tanhf(0.5f * x) + 0.5f;
}

__global__ __launch_bounds__(256, 1)
void nas_controller(const float* __restrict__ embed,
                    const float* __restrict__ w_ih,
                    const float* __restrict__ w_hh,
                    const float* __restrict__ b_ih,
                    const float* __restrict__ b_hh,
                    const float* __restrict__ w_soft,
                    const float* __restrict__ b_soft,
                    const float* __restrict__ b_soft_nl,
                    const float* __restrict__ w_attn1,
                    const float* __restrict__ w_attn2,
                    const float* __restrict__ v_attn,
                    const int* __restrict__ seedp,
                    float* __restrict__ out) {
  const int tid  = threadIdx.x;
  const int lane = tid & 63;
  const int wid  = tid >> 6;

  __shared__ float xs[64], hs[64], cs[64], gates[256];
  __shared__ float ancs[7][64];   // anchors (rows 0,1 stay zero)
  __shared__ float aw1s[7][64];   // anchors @ w_attn1.T
  __shared__ float hw2[64];       // h @ w_attn2.T
  __shared__ float lg[8];         // logits scratch
  __shared__ int   seli;
  __shared__ uint32_t skeys[40];  // 20 keys for the active sampler

  // LSTM weights resident in registers: thread t owns gate-row t.
  float wih[64], whh[64];
  {
    const float4* wi4 = reinterpret_cast<const float4*>(w_ih) + tid * 16;
    const float4* wh4 = reinterpret_cast<const float4*>(w_hh) + tid * 16;
#pragma unroll
    for (int j = 0; j < 16; ++j) {
      float4 a = wi4[j];
      wih[4*j+0] = a.x; wih[4*j+1] = a.y; wih[4*j+2] = a.z; wih[4*j+3] = a.w;
      float4 b = wh4[j];
      whh[4*j+0] = b.x; whh[4*j+1] = b.y; whh[4*j+2] = b.z; whh[4*j+3] = b.w;
    }
  }
  const float bih = b_ih[tid];
  const float bhh = b_hh[tid];
  const float va  = v_attn[lane];

  if (tid < 64) {
    hs[tid] = 0.f; cs[tid] = 0.f;
    ancs[0][tid] = 0.f; ancs[1][tid] = 0.f;
  }

  // Root key derivation (thread 0 registers)
  uint32_t k1a = 0, k1b = 0, k2a = 0, k2b = 0;
  if (tid == 0) {
    uint32_t seed = (uint32_t)seedp[0];
#if JAX_PARTITIONABLE
    tf2x32(0u, seed, 0u, 0u, k1a, k1b);   // split(key)[0]
    tf2x32(0u, seed, 0u, 1u, k2a, k2b);   // split(key)[1]
#else
    uint32_t a0, b0, a1, b1;
    tf2x32(0u, seed, 0u, 2u, a0, b0);
    tf2x32(0u, seed, 1u, 3u, a1, b1);
    k1a = a0; k1b = a1; k2a = b0; k2b = b1;
#endif
  }

  float lp = 0.f, ent = 0.f;           // thread-0 accumulators (per sampler)
  float lp_prev = 0.f, ent_prev = 0.f; // sampler-1 totals

  auto lstm = [&]() {
    __syncthreads();                   // xs/hs/cs stable
    float acc = 0.f;
#pragma unroll
    for (int j = 0; j < 64; ++j) acc = fmaf(wih[j], xs[j], acc);
    acc += bih;
#pragma unroll
    for (int j = 0; j < 64; ++j) acc = fmaf(whh[j], hs[j], acc);
    acc += bhh;
    gates[tid] = acc;
    __syncthreads();
    if (tid < 64) {
      float c2 = sigf(gates[64+tid]) * cs[tid] + sigf(gates[tid]) * tanhf(gates[128+tid]);
      float h2 = sigf(gates[192+tid]) * tanhf(c2);
      cs[tid] = c2; hs[tid] = h2;
    }
    __syncthreads();
  };

  // dst[r] = dot(W[r,:], hs) for r=0..63, 4 threads per row.
  auto matvec64 = [&](const float* __restrict__ W, float* dst) {
    const int r = tid >> 2, q = tid & 3;
    const float4* w4 = reinterpret_cast<const float4*>(W + r * 64 + q * 16);
    float acc = 0.f;
#pragma unroll
    for (int j4 = 0; j4 < 4; ++j4) {
      float4 wv = w4[j4];
      const int jb = q * 16 + j4 * 4;
      acc = fmaf(wv.x, hs[jb+0], acc);
      acc = fmaf(wv.y, hs[jb+1], acc);
      acc = fmaf(wv.z, hs[jb+2], acc);
      acc = fmaf(wv.w, hs[jb+3], acc);
    }
    acc += __shfl_xor(acc, 1);
    acc += __shfl_xor(acc, 2);
    if (q == 0) dst[r] = acc;
    __syncthreads();
  };

  // Thread-0 serial: gumbel-max categorical over lg[0..n-1] with skeys[k],
  // plus log_prob / entropy accumulation. Returns sampled index.
  auto sample_t0 = [&](int n, int k) -> int {
    const uint32_t ka = skeys[2*k], kb = skeys[2*k+1];
    const float TINYF = 1.1754943508222875e-38f;
    float best = -3.4e38f; int bi = 0;
#if JAX_PARTITIONABLE
    for (int i = 0; i < n; ++i) {
      uint32_t o0, o1;
      tf2x32(ka, kb, 0u, (uint32_t)i, o0, o1);
      uint32_t b = o0 ^ o1;
      float u = __uint_as_float((b >> 9) | 0x3f800000u) - 1.0f;
      u = u * (1.0f - TINYF) + TINYF;
      u = fmaxf(TINYF, u);
      float g = -logf(-logf(u));
      float v = lg[i] + g;
      if (v > best) { best = v; bi = i; }
    }
#else
    const int hh = (n + 1) >> 1;       // legacy iota-halves layout (odd padded)
    for (int i = 0; i < n; ++i) {
      const int pr = (i < hh) ? i : (i - hh);
      const uint32_t c1 = (hh + pr < n) ? (uint32_t)(hh + pr) : 0u;
      uint32_t o0, o1;
      tf2x32(ka, kb, (uint32_t)pr, c1, o0, o1);
      uint32_t b = (i < hh) ? o0 : o1;
      float u = __uint_as_float((b >> 9) | 0x3f800000u) - 1.0f;
      u = u * (1.0f - TINYF) + TINYF;
      u = fmaxf(TINYF, u);
      float g = -logf(-logf(u));
      float v = lg[i] + g;
      if (v > best) { best = v; bi = i; }
    }
#endif
    float mx = lg[0];
    for (int i = 1; i < n; ++i) mx = fmaxf(mx, lg[i]);
    float ssum = 0.f;
    for (int i = 0; i < n; ++i) ssum += expf(lg[i] - mx);
    float lse = logf(ssum);
    lp += -((lg[bi] - mx) - lse);
    float eacc = 0.f;
    for (int i = 0; i < n; ++i) {
      float lpi = (lg[i] - mx) - lse;
      eacc += lpi * expf(lpi);
    }
    ent += -eacc;
    return bi;
  };

  for (int s = 0; s < 2; ++s) {
    if (tid == 0) {
      const uint32_t ka = s ? k2a : k1a;
      const uint32_t kb = s ? k2b : k1b;
#if JAX_PARTITIONABLE
      for (int j = 0; j < 20; ++j) {
        uint32_t o0, o1;
        tf2x32(ka, kb, 0u, (uint32_t)j, o0, o1);
        skeys[2*j] = o0; skeys[2*j+1] = o1;
      }
#else
      for (int i = 0; i < 20; ++i) {
        uint32_t o0, o1;
        tf2x32(ka, kb, (uint32_t)i, (uint32_t)(20 + i), o0, o1);
        skeys[i] = o0; skeys[20 + i] = o1;   // keys[j] = (skeys[2j], skeys[2j+1])
      }
#endif
      lp = 0.f; ent = 0.f;
    }
    if (tid < 64) xs[tid] = embed[tid];      // inputs = embed[0]

    // warmup: 2 anchor slots
    for (int w = 0; w < 2; ++w) {
      lstm();
      matvec64(w_attn1, aw1s[w]);
    }

    int keyk = 0;
    for (int L = 2; L <= 6; ++L) {
      // --- 2 index samples via attention ---
      for (int t = 0; t < 2; ++t) {
        lstm();
        matvec64(w_attn2, hw2);
        for (int r = wid; r < L; r += 4) {
          float v = tanhf(aw1s[r][lane] + hw2[lane]) * va;
          v += __shfl_xor(v, 32);
          v += __shfl_xor(v, 16);
          v += __shfl_xor(v, 8);
          v += __shfl_xor(v, 4);
          v += __shfl_xor(v, 2);
          v += __shfl_xor(v, 1);
          if (lane == 0) lg[r] = v;
        }
        __syncthreads();
        if (tid == 0) {
          for (int r = 0; r < L; ++r) {
            float l = lg[r];
            lg[r] = l / 5.0f + 1.1f * tanhf(l);
          }
          int c = sample_t0(L, keyk);
          seli = c;
          out[s*20 + (L-2)*4 + t*2] = (float)c;
        }
        keyk++;
        __syncthreads();
        if (tid < 64) xs[tid] = ancs[seli][tid];   // inputs = anchors[index]
      }
      // --- 2 op samples ---
      for (int t = 0; t < 2; ++t) {
        lstm();
        for (int r = wid; r < 5; r += 4) {
          float v = w_soft[r*64 + lane] * hs[lane];
          v += __shfl_xor(v, 32);
          v += __shfl_xor(v, 16);
          v += __shfl_xor(v, 8);
          v += __shfl_xor(v, 4);
          v += __shfl_xor(v, 2);
          v += __shfl_xor(v, 1);
          if (lane == 0) lg[r] = v + b_soft[r];
        }
        __syncthreads();
        if (tid == 0) {
          for (int r = 0; r < 5; ++r) {
            float l = lg[r];
            l = (float)(1.1 / 2.5) * tanhf(l / 5.0f);
            if (s == 0) l += b_soft_nl[r];          // use_bias only in sampler 1
            lg[r] = l;
          }
          int c = sample_t0(5, keyk);
          seli = c;
          out[s*20 + (L-2)*4 + t*2 + 1] = (float)c;
        }
        keyk++;
        __syncthreads();
        if (tid < 64) xs[tid] = embed[(seli + 1) * 64 + tid];
      }
      // --- anchor step ---
      lstm();
      if (tid < 64) ancs[L][tid] = hs[tid];
      matvec64(w_attn1, aw1s[L]);
      if (tid < 64) xs[tid] = embed[tid];
    }

    if (tid == 0) {
      if (s == 0) { lp_prev = lp; ent_prev = ent; }
      else        { out[40] = lp_prev + lp; out[41] = ent_prev + ent; }
    }
    __syncthreads();
  }
}

extern "C" void kernel_launch(void* const* d_in, const int* in_sizes, int n_in,
                              void* d_out, int out_size, void* d_ws, size_t ws_size,
                              hipStream_t stream) {
  (void)in_sizes; (void)n_in; (void)out_size; (void)d_ws; (void)ws_size;
  nas_controller<<<1, 256, 0, stream>>>(
      (const float*)d_in[0],  // embed
      (const float*)d_in[1],  // w_ih
      (const float*)d_in[2],  // w_hh
      (const float*)d_in[3],  // b_ih
      (const float*)d_in[4],  // b_hh
      (const float*)d_in[5],  // w_soft
      (const float*)d_in[6],  // b_soft
      (const float*)d_in[7],  // b_soft_no_learn
      (const float*)d_in[8],  // w_attn1
      (const float*)d_in[9],  // w_attn2
      (const float*)d_in[10], // v_attn
      (const int*)d_in[11],   // seed
      (float*)d_out);
}

// Round 2
// 104.088 us; speedup vs baseline: 1.9774x; 1.9774x over previous
//
#include <hip/hip_runtime.h>
#include <cstdint>

// 1 = fast transcendentals (__expf/__logf/rcp-based tanh). If arcs flip
// (integer-valued absmax error), set to 0 to restore libm bit-exact path.
#ifndef FASTMATH
#define FASTMATH 1
#endif

#define NT 512

__device__ __forceinline__ uint32_t rotl32_(uint32_t v, int d) {
  return (v << d) | (v >> (32 - d));
}

// Threefry-2x32, 20 rounds, exactly JAX's schedule (partitionable mode).
__device__ __forceinline__ void tf2x32(uint32_t k0, uint32_t k1,
                                       uint32_t x0, uint32_t x1,
                                       uint32_t& o0, uint32_t& o1) {
  const uint32_t k2 = k0 ^ k1 ^ 0x1BD11BDAu;
  x0 += k0; x1 += k1;
#define TF4(a,b,c,d) \
  x0 += x1; x1 = rotl32_(x1,a); x1 ^= x0; \
  x0 += x1; x1 = rotl32_(x1,b); x1 ^= x0; \
  x0 += x1; x1 = rotl32_(x1,c); x1 ^= x0; \
  x0 += x1; x1 = rotl32_(x1,d); x1 ^= x0;
  TF4(13,15,26,6)
  x0 += k1; x1 += k2 + 1u;
  TF4(17,29,16,24)
  x0 += k2; x1 += k0 + 2u;
  TF4(13,15,26,6)
  x0 += k0; x1 += k1 + 3u;
  TF4(17,29,16,24)
  x0 += k1; x1 += k2 + 4u;
  TF4(13,15,26,6)
  x0 += k2; x1 += k0 + 5u;
#undef TF4
  o0 = x0; o1 = x1;
}

#if FASTMATH
__device__ __forceinline__ float tanh_(float x) {
  float e = __expf(2.0f * x);                 // v_exp_f32
  return 1.0f - __fdividef(2.0f, e + 1.0f);   // v_rcp + mul
}
__device__ __forceinline__ float sig_(float x) {
  return __fdividef(1.0f, 1.0f + __expf(-x));
}
#define log_ __logf
#define exp_ __expf
#else
__device__ __forceinline__ float tanh_(float x) { return tanhf(x); }
__device__ __forceinline__ float sig_(float x) { return 0.5f * tanhf(0.5f * x) + 0.5f; }
#define log_ logf
#define exp_ expf
#endif

__global__ __launch_bounds__(NT, 2)
void nas_controller(const float* __restrict__ embed,
                    const float* __restrict__ w_ih,
                    const float* __restrict__ w_hh,
                    const float* __restrict__ b_ih,
                    const float* __restrict__ b_hh,
                    const float* __restrict__ w_soft,
                    const float* __restrict__ b_soft,
                    const float* __restrict__ b_soft_nl,
                    const float* __restrict__ w_attn1,
                    const float* __restrict__ w_attn2,
                    const float* __restrict__ v_attn,
                    const int* __restrict__ seedp,
                    float* __restrict__ out) {
  const int tid  = threadIdx.x;
  const int lane = tid & 63;
  const int wid  = tid >> 6;
  const int row  = tid >> 1;   // gate row 0..255
  const int half = tid & 1;    // which 32-wide half of the 64-dim reduction

  __shared__ __align__(16) float xh[128];        // [0..63]=x, [64..127]=h
  __shared__ float cs[64];
  __shared__ float gates[256];
  __shared__ __align__(16) float ancs[7][64];    // anchors (rows 0,1 stay zero)
  __shared__ __align__(16) float aw1s[7][64];    // anchors @ w_attn1.T
  __shared__ __align__(16) float hw2[64];        // h @ w_attn2.T
  __shared__ float lg[8];                        // raw logits scratch
  __shared__ int   seli;
  __shared__ uint32_t rk[4];                     // two split root keys
  __shared__ uint32_t skeys[2][40];              // 2 samplers x 20 keys x 2 words
  __shared__ __align__(16) float attn1L[64 * 68];  // stride 68 = conflict-free b128
  __shared__ __align__(16) float attn2L[64 * 68];
  __shared__ float wsoftL[5 * 64];
  __shared__ __align__(16) float embedL[6 * 64];
  __shared__ float bsoftL[5], bnlL[5];

  // ---- stage weights to LDS / derive root keys (one-time) ----
  for (int i4 = tid; i4 < 1024; i4 += NT) {
    int r = i4 >> 4, c4 = i4 & 15;
    reinterpret_cast<float4*>(attn1L)[r * 17 + c4] =
        reinterpret_cast<const float4*>(w_attn1)[i4];
    reinterpret_cast<float4*>(attn2L)[r * 17 + c4] =
        reinterpret_cast<const float4*>(w_attn2)[i4];
  }
  if (tid < 320) wsoftL[tid] = w_soft[tid];
  if (tid < 384) embedL[tid] = embed[tid];
  if (tid < 5) { bsoftL[tid] = b_soft[tid]; bnlL[tid] = b_soft_nl[tid]; }
  if (tid < 64) { cs[tid] = 0.f; xh[64 + tid] = 0.f; ancs[0][tid] = 0.f; ancs[1][tid] = 0.f; }
  if (tid < 2) {
    uint32_t o0, o1;
    tf2x32(0u, (uint32_t)seedp[0], 0u, (uint32_t)tid, o0, o1);  // split(key)[tid]
    rk[2 * tid] = o0; rk[2 * tid + 1] = o1;
  }
  __syncthreads();
  if (tid < 40) {  // all 40 sample keys in parallel: split(k_s, 20)[j]
    int s = tid / 20, j = tid % 20;
    uint32_t o0, o1;
    tf2x32(rk[2 * s], rk[2 * s + 1], 0u, (uint32_t)j, o0, o1);
    skeys[s][2 * j] = o0; skeys[s][2 * j + 1] = o1;
  }

  // ---- LSTM weights register-resident: 2 threads per gate row, 64 floats each ----
  float4 wi[8], wh[8];
  {
    const float4* wb = reinterpret_cast<const float4*>(w_ih) + row * 16 + half * 8;
#pragma unroll
    for (int j = 0; j < 8; ++j) wi[j] = wb[j];
    const float4* hb = reinterpret_cast<const float4*>(w_hh) + row * 16 + half * 8;
#pragma unroll
    for (int j = 0; j < 8; ++j) wh[j] = hb[j];
  }
  const float bsum = b_ih[row] + b_hh[row];
  const float va   = v_attn[lane];

  float lp = 0.f, ent = 0.f;   // thread-0 accumulators across BOTH samplers

  auto lstm = [&]() {
    __syncthreads();           // xh/cs stable
    float ax = 0.f, ay = 0.f, az = 0.f, aw = 0.f;
    const float4* x4 = reinterpret_cast<const float4*>(xh) + half * 8;
#pragma unroll
    for (int j = 0; j < 8; ++j) {
      float4 x = x4[j], w = wi[j];
      ax = fmaf(w.x, x.x, ax); ay = fmaf(w.y, x.y, ay);
      az = fmaf(w.z, x.z, az); aw = fmaf(w.w, x.w, aw);
    }
    const float4* h4 = reinterpret_cast<const float4*>(xh) + 16 + half * 8;
#pragma unroll
    for (int j = 0; j < 8; ++j) {
      float4 x = h4[j], w = wh[j];
      ax = fmaf(w.x, x.x, ax); ay = fmaf(w.y, x.y, ay);
      az = fmaf(w.z, x.z, az); aw = fmaf(w.w, x.w, aw);
    }
    float acc = (ax + ay) + (az + aw);
    acc += __shfl_xor(acc, 1);               // combine the two halves of the row
    if (half == 0) gates[row] = acc + bsum;
    __syncthreads();
    if (tid < 64) {
      float gi = gates[tid], gf = gates[64 + tid], gg = gates[128 + tid], go = gates[192 + tid];
      float c2 = sig_(gf) * cs[tid] + sig_(gi) * tanh_(gg);
      float h2 = sig_(go) * tanh_(c2);
      cs[tid] = c2; xh[64 + tid] = h2;
    }
    __syncthreads();
  };

  // dst[r] = dot(Wl[r,:], h) ; Wl is LDS with row stride 68. 8 threads/row.
  auto matvec64 = [&](const float* Wl, float* dst) {
    const int r = tid >> 3, q = tid & 7;
    const float4* w4 = reinterpret_cast<const float4*>(Wl + r * 68 + q * 8);
    float4 wa = w4[0], wb = w4[1];
    const float4* h4 = reinterpret_cast<const float4*>(xh) + 16;
    float4 ha = h4[q * 2], hb = h4[q * 2 + 1];
    float acc = fmaf(wa.x, ha.x, fmaf(wa.y, ha.y, fmaf(wa.z, ha.z, wa.w * ha.w)));
    acc += fmaf(wb.x, hb.x, fmaf(wb.y, hb.y, fmaf(wb.z, hb.z, wb.w * hb.w)));
    acc += __shfl_xor(acc, 1);
    acc += __shfl_xor(acc, 2);
    acc += __shfl_xor(acc, 4);
    if (q == 0) dst[r] = acc;
    __syncthreads();
  };

  // Lane-parallel Gumbel-max categorical + log_prob/entropy on wave 0.
  // mode: 0 = attention transform, 1 = op transform + bias, 2 = op transform.
  // Caller must sync before (lg ready); this syncs after (seli ready).
  auto sample = [&](int n, int s, int k, int mode, float* outp) {
    if (wid == 0) {
      const uint32_t ka = skeys[s][2 * k], kb = skeys[s][2 * k + 1];
      float l;
      if (lane < n) {
        float raw = lg[lane];
        if (mode == 0) l = raw / 5.0f + 1.1f * tanh_(raw);
        else {
          l = (float)(1.1 / 2.5) * tanh_(raw / 5.0f);
          if (mode == 1) l += bnlL[lane];
        }
      } else l = -INFINITY;
      // gumbel per candidate (parallel threefry)
      float v; int bi;
      if (lane < n) {
        uint32_t o0, o1;
        tf2x32(ka, kb, 0u, (uint32_t)lane, o0, o1);
        uint32_t b = o0 ^ o1;
        const float TINY = 1.1754943508222875e-38f;
        float u = __uint_as_float((b >> 9) | 0x3f800000u) - 1.0f;
        u = u * (1.0f - TINY) + TINY;
        u = fmaxf(TINY, u);
        float g = -log_(-log_(u));
        v = l + g; bi = lane;
      } else { v = -INFINITY; bi = 0x7fffffff; }
      // argmax, first-index tie-break, width-8 groups
#pragma unroll
      for (int m = 4; m >= 1; m >>= 1) {
        float ov = __shfl_xor(v, m, 8);
        int   oi = __shfl_xor(bi, m, 8);
        if (ov > v || (ov == v && oi < bi)) { v = ov; bi = oi; }
      }
      // log_softmax stats
      float mx = l;
#pragma unroll
      for (int m = 4; m >= 1; m >>= 1) mx = fmaxf(mx, __shfl_xor(mx, m, 8));
      float e = (lane < n) ? exp_(l - mx) : 0.f;
      float ss = e;
#pragma unroll
      for (int m = 4; m >= 1; m >>= 1) ss += __shfl_xor(ss, m, 8);
      float lse = log_(ss);
      float lb  = __shfl(l, bi, 8);
      float lpi = l - mx - lse;
      float ec  = (lane < n) ? lpi * exp_(lpi) : 0.f;
#pragma unroll
      for (int m = 4; m >= 1; m >>= 1) ec += __shfl_xor(ec, m, 8);
      if (lane == 0) {
        lp  += -(lb - mx - lse);
        ent += -ec;
        seli = bi;
        *outp = (float)bi;
      }
    }
    __syncthreads();
  };

  for (int s = 0; s < 2; ++s) {
    if (tid < 64) xh[tid] = embedL[tid];          // inputs = embed[0]
    for (int w = 0; w < 2; ++w) { lstm(); matvec64(attn1L, aw1s[w]); }

    int keyk = 0;
    for (int L = 2; L <= 6; ++L) {
      // --- 2 index samples via attention ---
      for (int t = 0; t < 2; ++t) {
        lstm();
        matvec64(attn2L, hw2);
        if (wid < L) {                            // one wave per candidate row
          float vv = tanh_(aw1s[wid][lane] + hw2[lane]) * va;
          vv += __shfl_xor(vv, 32); vv += __shfl_xor(vv, 16); vv += __shfl_xor(vv, 8);
          vv += __shfl_xor(vv, 4);  vv += __shfl_xor(vv, 2);  vv += __shfl_xor(vv, 1);
          if (lane == 0) lg[wid] = vv;
        }
        __syncthreads();
        sample(L, s, keyk, 0, out + s * 20 + (L - 2) * 4 + t * 2);
        keyk++;
        if (tid < 64) xh[tid] = ancs[seli][tid];  // inputs = anchors[index]
      }
      // --- 2 op samples ---
      for (int t = 0; t < 2; ++t) {
        lstm();
        if (wid < 5) {
          float vv = wsoftL[wid * 64 + lane] * xh[64 + lane];
          vv += __shfl_xor(vv, 32); vv += __shfl_xor(vv, 16); vv += __shfl_xor(vv, 8);
          vv += __shfl_xor(vv, 4);  vv += __shfl_xor(vv, 2);  vv += __shfl_xor(vv, 1);
          if (lane == 0) lg[wid] = vv + bsoftL[wid];
        }
        __syncthreads();
        sample(5, s, keyk, (s == 0) ? 1 : 2, out + s * 20 + (L - 2) * 4 + t * 2 + 1);
        keyk++;
        if (tid < 64) xh[tid] = embedL[(seli + 1) * 64 + tid];
      }
      // --- anchor step ---
      lstm();
      if (tid < 64) ancs[L][tid] = xh[64 + tid];
      matvec64(attn1L, aw1s[L]);
      if (tid < 64) xh[tid] = embedL[tid];
    }
  }

  if (tid == 0) { out[40] = lp; out[41] = ent; }
}

extern "C" void kernel_launch(void* const* d_in, const int* in_sizes, int n_in,
                              void* d_out, int out_size, void* d_ws, size_t ws_size,
                              hipStream_t stream) {
  (void)in_sizes; (void)n_in; (void)out_size; (void)d_ws; (void)ws_size;
  nas_controller<<<1, NT, 0, stream>>>(
      (const float*)d_in[0],  // embed
      (const float*)d_in[1],  // w_ih
      (const float*)d_in[2],  // w_hh
      (const float*)d_in[3],  // b_ih
      (const float*)d_in[4],  // b_hh
      (const float*)d_in[5],  // w_soft
      (const float*)d_in[6],  // b_soft
      (const float*)d_in[7],  // b_soft_no_learn
      (const float*)d_in[8],  // w_attn1
      (const float*)d_in[9],  // w_attn2
      (const float*)d_in[10], // v_attn
      (const int*)d_in[11],   // seed
      (float*)d_out);
}

// Round 3
// 75.478 us; speedup vs baseline: 2.7269x; 1.3791x over previous
//
#include <hip/hip_runtime.h>
#include <cstdint>

// 1 = fast transcendentals. Set 0 to restore libm path if arcs flip.
#ifndef FASTMATH
#define FASTMATH 1
#endif

#define NT 512

__device__ __forceinline__ uint32_t rotl32_(uint32_t v, int d) {
  return (v << d) | (v >> (32 - d));
}

// Threefry-2x32, 20 rounds, JAX partitionable-mode semantics.
__device__ __forceinline__ void tf2x32(uint32_t k0, uint32_t k1,
                                       uint32_t x0, uint32_t x1,
                                       uint32_t& o0, uint32_t& o1) {
  const uint32_t k2 = k0 ^ k1 ^ 0x1BD11BDAu;
  x0 += k0; x1 += k1;
#define TF4(a,b,c,d) \
  x0 += x1; x1 = rotl32_(x1,a); x1 ^= x0; \
  x0 += x1; x1 = rotl32_(x1,b); x1 ^= x0; \
  x0 += x1; x1 = rotl32_(x1,c); x1 ^= x0; \
  x0 += x1; x1 = rotl32_(x1,d); x1 ^= x0;
  TF4(13,15,26,6)
  x0 += k1; x1 += k2 + 1u;
  TF4(17,29,16,24)
  x0 += k2; x1 += k0 + 2u;
  TF4(13,15,26,6)
  x0 += k0; x1 += k1 + 3u;
  TF4(17,29,16,24)
  x0 += k1; x1 += k2 + 4u;
  TF4(13,15,26,6)
  x0 += k2; x1 += k0 + 5u;
#undef TF4
  o0 = x0; o1 = x1;
}

#if FASTMATH
__device__ __forceinline__ float tanh_(float x) {
  float e = __expf(2.0f * x);
  return 1.0f - __fdividef(2.0f, e + 1.0f);
}
__device__ __forceinline__ float sig_(float x) {
  return __fdividef(1.0f, 1.0f + __expf(-x));
}
#define log_ __logf
#define exp_ __expf
#else
__device__ __forceinline__ float tanh_(float x) { return tanhf(x); }
__device__ __forceinline__ float sig_(float x) { return 0.5f * tanhf(0.5f * x) + 0.5f; }
#define log_ logf
#define exp_ expf
#endif

// DPP helpers (full row/bank masks, bound_ctrl=1). Pure lane permutes.
template <int CTRL>
__device__ __forceinline__ float dppf(float x) {
  return __int_as_float(__builtin_amdgcn_update_dpp(
      0, __float_as_int(x), CTRL, 0xF, 0xF, true));
}
template <int CTRL>
__device__ __forceinline__ int dppi(int x) {
  return __builtin_amdgcn_update_dpp(0, x, CTRL, 0xF, 0xF, true);
}
constexpr int QP1 = 0xB1;   // quad_perm [1,0,3,2] : lane^1
constexpr int QP2 = 0x4E;   // quad_perm [2,3,0,1] : lane^2
constexpr int HM  = 0x141;  // row_half_mirror     : lane^7

__global__ __launch_bounds__(NT, 2)
void nas_controller(const float* __restrict__ embed,
                    const float* __restrict__ w_ih,
                    const float* __restrict__ w_hh,
                    const float* __restrict__ b_ih,
                    const float* __restrict__ b_hh,
                    const float* __restrict__ w_soft,
                    const float* __restrict__ b_soft,
                    const float* __restrict__ b_soft_nl,
                    const float* __restrict__ w_attn1,
                    const float* __restrict__ w_attn2,
                    const float* __restrict__ v_attn,
                    const int* __restrict__ seedp,
                    float* __restrict__ out) {
  const int tid  = threadIdx.x;
  const int lane = tid & 63;
  const int wid  = tid >> 6;

  // LSTM lane mapping: 8 lanes per hidden unit u: (role i/g/f/o) x (half hh)
  const int hh   = lane & 1;
  const int role = (lane >> 1) & 3;              // 0:i 1:g 2:f 3:o
  const int ul   = lane >> 3;
  const int u    = (wid << 3) | ul;              // hidden unit 0..63
  const int rblk = (0x3120 >> (4 * role)) & 0xF; // ref gate block: i0 f1 g2 o3
  const int refrow = rblk * 64 + u;

  __shared__ __align__(16) float attn1L[64 * 68];
  __shared__ __align__(16) float attn2L[64 * 68];
  __shared__ __align__(16) float wsoftL[5 * 68];
  __shared__ __align__(16) float aw1sF[7 * 68];   // anchors @ w_attn1.T (padded)
  __shared__ __align__(16) float hw2[64];         // h @ w_attn2.T
  __shared__ __align__(16) float hL[2][64];       // double-buffered h
  __shared__ __align__(16) float preL[13 * 256];  // W_ih@x per src slot, [u][role]
  __shared__ float gL[320];                       // precomputed gumbels [s][k][i]
  __shared__ float vaL[64];
  __shared__ float bsoftL[8], bnlL[8];
  __shared__ int   seliL;

  // ---- one-time staging ----
  for (int i4 = tid; i4 < 1024; i4 += NT) {       // 64x64 in float4s, pad 68
    int r = i4 >> 4, c4 = i4 & 15;
    reinterpret_cast<float4*>(attn1L)[r * 17 + c4] =
        reinterpret_cast<const float4*>(w_attn1)[i4];
    reinterpret_cast<float4*>(attn2L)[r * 17 + c4] =
        reinterpret_cast<const float4*>(w_attn2)[i4];
  }
  if (tid < 320) { int r = tid >> 6, c = tid & 63; wsoftL[r * 68 + c] = w_soft[tid]; }
  if (tid < 64) { vaL[tid] = v_attn[tid]; hL[0][tid] = 0.f; hL[1][tid] = 0.f; }
  if (tid < 8) {
    bsoftL[tid] = (tid < 5) ? b_soft[tid] : 0.f;
    bnlL[tid]   = (tid < 5) ? b_soft_nl[tid] : 0.f;
  }
  for (int i = tid; i < 512; i += NT) preL[6 * 256 + i] = 0.f;  // anchors 0,1 = 0

  // Gumbels for all 40 samples x 8 candidates, fully parallel, off the chain.
  if (tid < 320) {
    int s = tid >= 160 ? 1 : 0;
    int rem = tid - s * 160;
    int k = rem >> 3, i = rem & 7;
    uint32_t a, b, ka, kb, o0, o1;
    tf2x32(0u, (uint32_t)seedp[0], 0u, (uint32_t)s, a, b);   // split(root)[s]
    tf2x32(a, b, 0u, (uint32_t)k, ka, kb);                   // split(k_s,20)[k]
    tf2x32(ka, kb, 0u, (uint32_t)i, o0, o1);                 // random_bits
    uint32_t bits = o0 ^ o1;
    const float TINY = 1.1754943508222875e-38f;
    float uu = __uint_as_float((bits >> 9) | 0x3f800000u) - 1.0f;
    uu = uu * (1.0f - TINY) + TINY;
    uu = fmaxf(TINY, uu);
    gL[tid] = -log_(-log_(uu));
  }

  // ---- LSTM weights register-resident: half a gate row per lane ----
  float4 wi[8], wh[8];
  {
    const float4* a = reinterpret_cast<const float4*>(w_ih) + refrow * 16 + hh * 8;
#pragma unroll
    for (int j = 0; j < 8; ++j) wi[j] = a[j];
    const float4* b = reinterpret_cast<const float4*>(w_hh) + refrow * 16 + hh * 8;
#pragma unroll
    for (int j = 0; j < 8; ++j) wh[j] = b[j];
  }
  const float bsum = b_ih[refrow] + b_hh[refrow];

  // Precompute W_ih @ embed[e] for slots 0..5.
#pragma unroll
  for (int e = 0; e < 6; ++e) {
    const float4* x4 = reinterpret_cast<const float4*>(embed) + e * 16 + hh * 8;
    float ax = 0, ay = 0, az = 0, aw = 0;
#pragma unroll
    for (int j = 0; j < 8; ++j) {
      float4 x = x4[j], w = wi[j];
      ax = fmaf(w.x, x.x, ax); ay = fmaf(w.y, x.y, ay);
      az = fmaf(w.z, x.z, az); aw = fmaf(w.w, x.w, aw);
    }
    float acc = (ax + ay) + (az + aw);
    float tot = acc + dppf<QP1>(acc);
    if (hh == 0) preL[e * 256 + u * 4 + role] = tot;
  }

  int curH = 0, srcSlot = 0;
  float creg = 0.f;
  float lp = 0.f, ent = 0.f;        // lane 0 of wave 0

  // One LSTM step: gates + nonlin + c/h update, all in-wave via DPP.
  auto lstm = [&]() {
    __syncthreads();
    const float4* h4 = reinterpret_cast<const float4*>(hL[curH]) + hh * 8;
    float ax = 0, ay = 0, az = 0, aw = 0;
#pragma unroll
    for (int j = 0; j < 8; ++j) {
      float4 x = h4[j], w = wh[j];
      ax = fmaf(w.x, x.x, ax); ay = fmaf(w.y, x.y, ay);
      az = fmaf(w.z, x.z, az); aw = fmaf(w.w, x.w, aw);
    }
    float acc = (ax + ay) + (az + aw);
    if (hh == 0) acc += preL[srcSlot * 256 + u * 4 + role] + bsum;
    float gs = acc + dppf<QP1>(acc);               // full gate preactivation
    float nl = (role == 1) ? tanh_(gs) : sig_(gs); // i,f,o: sig; g: tanh
    float other = dppf<QP2>(nl);                   // i<->g, f<->o exchange
    float P = (lane & 4) ? (((role == 2) ? nl : other) * creg)  // Sf * c
                         : (nl * other);                        // Si * Tg
    float c2 = P + dppf<HM>(P);                    // both quads -> c2 everywhere
    creg = c2;
    if (role == 3 && hh == 0) hL[curH ^ 1][u] = nl * tanh_(c2);
    curH ^= 1;
  };

  // dst[r] = dot(Wl[r,:], h), 8 lanes per row, DPP combine.
  auto matvec = [&](const float* Wl, float* dst) {
    const int r = tid >> 3, q = tid & 7;
    const float4* w4 = reinterpret_cast<const float4*>(Wl + r * 68) + q * 2;
    float4 wa = w4[0], wb = w4[1];
    const float4* h4 = reinterpret_cast<const float4*>(hL[curH]) + q * 2;
    float4 ha = h4[0], hb = h4[1];
    float acc = fmaf(wa.x, ha.x, fmaf(wa.y, ha.y, fmaf(wa.z, ha.z, wa.w * ha.w)));
    acc += fmaf(wb.x, hb.x, fmaf(wb.y, hb.y, fmaf(wb.z, hb.z, wb.w * hb.w)));
    acc += dppf<QP1>(acc); acc += dppf<QP2>(acc); acc += dppf<HM>(acc);
    if (q == 0) dst[r] = acc;
  };

  // Cache W_ih @ h (new anchor) into pre slot.
  auto anchorPre = [&](int slot) {
    const float4* h4 = reinterpret_cast<const float4*>(hL[curH]) + hh * 8;
    float ax = 0, ay = 0, az = 0, aw = 0;
#pragma unroll
    for (int j = 0; j < 8; ++j) {
      float4 x = h4[j], w = wi[j];
      ax = fmaf(w.x, x.x, ax); ay = fmaf(w.y, x.y, ay);
      az = fmaf(w.z, x.z, az); aw = fmaf(w.w, x.w, aw);
    }
    float acc = (ax + ay) + (az + aw);
    float tot = acc + dppf<QP1>(acc);
    if (hh == 0) preL[slot * 256 + u * 4 + role] = tot;
  };

  int sIdx = 0;
  // raw logits for candidates 0..7 sit in lanes 0..7 (wave 0 only).
  auto doSample = [&](int n, int k, int mode, float raw, float* op) {
    float l;
    if (lane < n) {
      if (mode == 0) l = raw / 5.0f + 1.1f * tanh_(raw);
      else {
        l = (float)(1.1 / 2.5) * tanh_(raw / 5.0f);
        if (mode == 1) l += bnlL[lane];
      }
    } else l = -INFINITY;
    float g = (lane < n) ? gL[sIdx * 160 + k * 8 + lane] : 0.f;
    float v = (lane < n) ? (l + g) : -INFINITY;
    int bi = lane & 7;
    float lw = l;
#define ARGSTEP(C) { float ov = dppf<C>(v), ol = dppf<C>(lw); int oi = dppi<C>(bi); \
    bool t = (ov > v) || (ov == v && oi < bi); if (t) { v = ov; lw = ol; bi = oi; } }
    ARGSTEP(QP1) ARGSTEP(QP2) ARGSTEP(HM)
#undef ARGSTEP
    float mx = l;
    mx = fmaxf(mx, dppf<QP1>(mx)); mx = fmaxf(mx, dppf<QP2>(mx)); mx = fmaxf(mx, dppf<HM>(mx));
    float e = (lane < n) ? exp_(l - mx) : 0.f;
    float ss = e; ss += dppf<QP1>(ss); ss += dppf<QP2>(ss); ss += dppf<HM>(ss);
    float lse = log_(ss);
    float lpi = l - mx - lse;
    float ec = (lane < n) ? lpi * exp_(lpi) : 0.f;
    ec += dppf<QP1>(ec); ec += dppf<QP2>(ec); ec += dppf<HM>(ec);
    if (lane == 0) {
      lp  += -(lw - mx - lse);
      ent += -ec;
      seliL = bi;
      op[0] = (float)bi;
    }
  };

  __syncthreads();

  for (int s = 0; s < 2; ++s) {
    sIdx = s;
    srcSlot = 0;
    for (int w = 0; w < 2; ++w) {                 // warmup anchors (zeros)
      lstm();
      __syncthreads();
      matvec(attn1L, aw1sF + w * 68);
    }
    int keyk = 0;
    for (int L = 2; L <= 6; ++L) {
      for (int t = 0; t < 2; ++t) {               // 2 index samples
        lstm();
        __syncthreads();
        matvec(attn2L, hw2);
        __syncthreads();
        if (wid == 0) {
          const int g8 = lane >> 3, j = lane & 7;
          float sacc = 0.f;
          if (g8 < L) {
#pragma unroll
            for (int e2 = 0; e2 < 8; ++e2) {
              int c = j * 8 + e2;
              sacc = fmaf(tanh_(aw1sF[g8 * 68 + c] + hw2[c]), vaL[c], sacc);
            }
          }
          sacc += dppf<QP1>(sacc); sacc += dppf<QP2>(sacc); sacc += dppf<HM>(sacc);
          float raw = __shfl(sacc, lane << 3);    // gather group sums to lanes 0..7
          doSample(L, keyk, 0, raw, out + s * 20 + (L - 2) * 4 + t * 2);
        }
        keyk++;
        __syncthreads();
        srcSlot = 6 + seliL;                      // x = anchors[index]
      }
      for (int t = 0; t < 2; ++t) {               // 2 op samples
        lstm();
        __syncthreads();
        if (wid == 0) {
          const int g8 = lane >> 3, j = lane & 7;
          float sacc = 0.f;
          if (g8 < 5) {
#pragma unroll
            for (int e2 = 0; e2 < 8; ++e2) {
              int c = j * 8 + e2;
              sacc = fmaf(wsoftL[g8 * 68 + c], hL[curH][c], sacc);
            }
          }
          sacc += dppf<QP1>(sacc); sacc += dppf<QP2>(sacc); sacc += dppf<HM>(sacc);
          float raw = __shfl(sacc, lane << 3) + bsoftL[lane & 7];
          doSample(5, keyk, (s == 0) ? 1 : 2, raw, out + s * 20 + (L - 2) * 4 + t * 2 + 1);
        }
        keyk++;
        __syncthreads();
        srcSlot = 1 + seliL;                      // x = embed[op+1]
      }
      lstm();                                     // anchor step
      __syncthreads();
      matvec(attn1L, aw1sF + L * 68);
      anchorPre(6 + L);
      srcSlot = 0;                                // x = embed[0]
    }
  }

  if (tid == 0) { out[40] = lp; out[41] = ent; }
}

extern "C" void kernel_launch(void* const* d_in, const int* in_sizes, int n_in,
                              void* d_out, int out_size, void* d_ws, size_t ws_size,
                              hipStream_t stream) {
  (void)in_sizes; (void)n_in; (void)out_size; (void)d_ws; (void)ws_size;
  nas_controller<<<1, NT, 0, stream>>>(
      (const float*)d_in[0],  // embed
      (const float*)d_in[1],  // w_ih
      (const float*)d_in[2],  // w_hh
      (const float*)d_in[3],  // b_ih
      (const float*)d_in[4],  // b_hh
      (const float*)d_in[5],  // w_soft
      (const float*)d_in[6],  // b_soft
      (const float*)d_in[7],  // b_soft_no_learn
      (const float*)d_in[8],  // w_attn1
      (const float*)d_in[9],  // w_attn2
      (const float*)d_in[10], // v_attn
      (const int*)d_in[11],   // seed
      (float*)d_out);
}